// Round 7
// baseline (963.410 us; speedup 1.0000x reference)
//
#include <hip/hip_runtime.h>

#define BB  256
#define TT  500
#define ENC 700
#define ENC_PAD 704   // rows 700..703 of w1t are zeros (gather padding target)
#define HID 128

// ---------------------------------------------------------------------------
// Kernel 1: transpose w1 (HID, ENC) -> w1t (ENC_PAD, HID); pad rows = 0
// ---------------------------------------------------------------------------
__global__ __launch_bounds__(128) void transpose_w1_kernel(const float* __restrict__ w1,
                                                           float* __restrict__ w1t) {
    int c = blockIdx.x;      // 0..ENC_PAD-1
    int h = threadIdx.x;     // 0..HID-1
    w1t[c * HID + h] = (c < ENC) ? w1[h * ENC + c] : 0.0f;
}

// ---------------------------------------------------------------------------
// Fused kernel v4: one block per b, 1024 threads (16 waves, 1 block/CU).
//   Round 5/6 lesson: at flat-wg=1024 hipcc pins VGPR=64 (8-wave/EU target)
//   and spills (~212 MB scratch writes); amdgpu_waves_per_eu(4,4) was
//   ignored. v4 fixes it by REDUCING DEMAND below 64:
//     - sequential row build (row A load+ballot fully, then row B reusing
//       the same 11 regs; sched_barrier(0) stops cross-row load hoisting)
//     - gather pipeline depth 8 -> 4 float4s (2 cols/iter). 4 in-flight
//       wave-wide loads x 14 producer waves = 56 KB/CU >> latency demand.
//   Accumulation chains still single ordered ascending-column per channel
//   -> bit-exact (absmax 0.0 preserved through all prior rounds).
//   Waves 2-15: producers (chunk k+1 -> LDS); waves 0-1: consumers
//   (recur's exact scan/reduce/layer-2 on chunk k).
//   LDS: 51.2K hb + 25.8K vbuf + 0.4K pbuf + 9.7K lists = 87.1 KB.
// ---------------------------------------------------------------------------
__global__ __launch_bounds__(1024, 4)
void fused_kernel(const float* __restrict__ x,
                  const float* __restrict__ w1t,
                  const float* __restrict__ w2,
                  float* __restrict__ out) {
    __shared__ float hb[2][50 * 128];     // 51.2 KB, chunk-sized h double buffer
    __shared__ float vbuf[50 * 129];      // 25.8 KB, stride 129 -> conflict-free
    __shared__ float pbuf[2][50];
    __shared__ ushort lists[32][152];     // 2 lists per wave

    const int tid  = threadIdx.x;         // 0..1023
    const int lane = tid & 63;
    const int wid  = tid >> 6;            // 0..15
    const int b    = blockIdx.x;
    const unsigned long long lt = (1ull << lane) - 1ull;

    const float D   = 0.95122942450071400910f;                                 // exp(-1/20)
    const float CD  = (float)(0.13591409142295226 * 0.95122942450071400910);   // (e/20)*d
    const float CRD = (float)(-0.27182818284590452 * 0.95122942450071400910);  // (-2e/20)*d

    // ---- build one row's ascending column list via ballot-compact ----
    // Loads live only within this call (11 VGPRs), reused across rows.
    auto build_list = [&](const float* xrow, ushort* list) -> int {
        int n = 0;
        #pragma unroll
        for (int k = 0; k < 11; ++k) {
            int c = k * 64 + lane;
            float xv = (c < ENC) ? xrow[c] : 0.0f;
            bool act = (xv != 0.0f);
            unsigned long long m = __ballot(act);
            if (act) {
                int pos = n + (int)__popcll(m & lt);
                if (pos < 144) list[pos] = (ushort)c;
            }
            n += (int)__popcll(m);
        }
        return n;
    };

    // ---- producer: compute h rows (t0, t0+1) of `chunk` into hb[buf] ----
    // Same arithmetic as the verified spmm4 gather; destination is LDS.
    auto produce_pair = [&](int buf, int chunk, int t0) {
        const int half = lane >> 5;               // 0 -> row A, 1 -> row B
        const int hl   = lane & 31;               // channels 4hl..4hl+3
        const float* xrowA = x + ((size_t)b * TT + (size_t)chunk * 50 + t0) * ENC;

        ushort* listA = lists[2 * wid + 0];
        ushort* listB = lists[2 * wid + 1];

        int nA = build_list(xrowA, listA);
        __builtin_amdgcn_sched_barrier(0);        // keep row-B loads out of row-A window
        int nB = build_list(xrowA + ENC, listB);
        __builtin_amdgcn_sched_barrier(0);

        nA = (nA < 144) ? nA : 144;
        nB = (nB < 144) ? nB : 144;
        int npmax = ((nA > nB ? nA : nB) + 3) & ~3;
        if (npmax < 4) npmax = 4;
        for (int p = nA + lane; p < npmax + 4; p += 64) listA[p] = (ushort)ENC;
        for (int p = nB + lane; p < npmax + 4; p += 64) listB[p] = (ushort)ENC;
        // wave-private lists; in-wave LDS RAW ordered by lgkmcnt

        const ushort* mylist = (half == 0) ? listA : listB;
        const float* wb = w1t + 4 * hl;

        // depth-4 pipeline: p0,p1 current, q0,q1 next (16 VGPRs)
        float a0 = 0.f, a1 = 0.f, a2 = 0.f, a3 = 0.f;
        int c0 = mylist[0], c1 = mylist[1];
        float4 p0 = *(const float4*)(wb + (size_t)c0 * HID);
        float4 p1 = *(const float4*)(wb + (size_t)c1 * HID);
        for (int j = 0; j < npmax; j += 2) {
            int d0 = mylist[j + 2], d1 = mylist[j + 3];
            float4 q0 = *(const float4*)(wb + (size_t)d0 * HID);
            float4 q1 = *(const float4*)(wb + (size_t)d1 * HID);
            // ordered ascending-column accumulation; 4 independent channel chains
            a0 += p0.x; a1 += p0.y; a2 += p0.z; a3 += p0.w;
            a0 += p1.x; a1 += p1.y; a2 += p1.z; a3 += p1.w;
            p0 = q0; p1 = q1;
        }
        // write h row (chunk-local t0+half) into LDS: contiguous 512 B per half
        float4* dst = (float4*)&hb[buf][(t0 + half) * 128] + hl;
        *dst = make_float4(a0, a1, a2, a3);
    };

    const float w2v = (tid < HID) ? w2[tid] : 0.0f;

    float ap = 0.f, aq = 0.f, rp = 0.f, rq = 0.f;   // layer-1, channel = tid (<128)
    float Ap = 0.f, Aq = 0.f, Rp = 0.f, Rq = 0.f;   // layer-2, redundant on consumer lanes

    // ---- prologue: all 16 waves fill chunk 0 (25 pairs) into hb[0] ----
    {
        produce_pair(0, 0, 2 * wid);
        if (wid + 16 < 25) produce_pair(0, 0, 2 * (wid + 16));
    }
    __syncthreads();

    for (int chunk = 0; chunk < 10; ++chunk) {
        const int cur = chunk & 1;

        if (wid >= 2) {
            // ---- 14 producer waves: chunk+1 (25 pairs, <=2 per wave) ----
            if (chunk < 9) {
                const int pw = wid - 2;               // 0..13
                produce_pair(cur ^ 1, chunk + 1, 2 * pw);
                if (pw + 14 < 25) produce_pair(cur ^ 1, chunk + 1, 2 * (pw + 14));
            }
        } else {
            // ---- consumers: layer-1 scan, 50 steps (arithmetic == recur v1) ----
            const float* hrow = &hb[cur][0];
            #pragma unroll
            for (int tl = 0; tl < 50; ++tl) {
                float h_ = hrow[tl * 128 + tid];
                float y = fmaf(D, aq, CD * ap);
                aq = y;
                ap = fmaf(D, ap, h_);
                float q = fmaf(D, rq, CRD * rp);
                float u = y + q;
                float s = (u >= 1.0f) ? 1.0f : 0.0f;
                rq = q;
                rp = fmaf(D, rp, s);
                vbuf[tl * 129 + tid] = s * w2v;     // per-channel partial of o_t
            }
        }
        __syncthreads();   // hb[cur^1] complete + vbuf ready

        // ---- reduce o_t: wave0 lanes 0..49 sum ch 0..63; wave1 ch 64..127 ----
        if (tid < 50) {
            const float* row = &vbuf[tid * 129];
            float a0 = 0.f, a1 = 0.f, a2 = 0.f, a3 = 0.f;
            #pragma unroll
            for (int k = 0; k < 64; k += 4) {
                a0 += row[k]; a1 += row[k + 1]; a2 += row[k + 2]; a3 += row[k + 3];
            }
            pbuf[0][tid] = (a0 + a1) + (a2 + a3);
        } else if (tid >= 64 && tid < 114) {
            const float* row = &vbuf[(tid - 64) * 129 + 64];
            float a0 = 0.f, a1 = 0.f, a2 = 0.f, a3 = 0.f;
            #pragma unroll
            for (int k = 0; k < 64; k += 4) {
                a0 += row[k]; a1 += row[k + 1]; a2 += row[k + 2]; a3 += row[k + 3];
            }
            pbuf[1][tid - 64] = (a0 + a1) + (a2 + a3);
        }
        __syncthreads();

        // ---- consumers: layer-2, 50 serial steps (overlaps next produce) ----
        if (tid < 128) {
            float my_s2 = 0.f;
            #pragma unroll
            for (int tl = 0; tl < 50; ++tl) {
                float ot = pbuf[0][tl] + pbuf[1][tl];
                float y2 = fmaf(D, Aq, CD * Ap);
                Aq = y2;
                Ap = fmaf(D, Ap, ot);
                float q2 = fmaf(D, Rq, CRD * Rp);
                float u2 = y2 + q2;
                float s2 = (u2 >= 1.0f) ? 1.0f : 0.0f;
                Rq = q2;
                Rp = fmaf(D, Rp, s2);
                if (tl == tid) my_s2 = s2;
            }
            if (tid < 50) out[(size_t)b * TT + chunk * 50 + tid] = my_s2;
        }
        // safety: producers racing ahead write hb[old cur] (consumers finished
        // it before this chunk's first barrier) and their own wave-private
        // lists; pbuf is only rewritten after the NEXT chunk's first barrier,
        // which lagging layer-2 threads must reach first.
    }
}

// ---------------------------------------------------------------------------
extern "C" void kernel_launch(void* const* d_in, const int* in_sizes, int n_in,
                              void* d_out, int out_size, void* d_ws, size_t ws_size,
                              hipStream_t stream) {
    const float* x  = (const float*)d_in[0];   // (B, T, ENC) binary fp32
    const float* w1 = (const float*)d_in[1];   // (HID, ENC)
    const float* w2 = (const float*)d_in[2];   // (1, HID)
    float* out = (float*)d_out;                // (B, T, 1)

    float* w1t = (float*)d_ws;                 // (ENC_PAD, HID) = 360 KB

    hipLaunchKernelGGL(transpose_w1_kernel, dim3(ENC_PAD), dim3(HID), 0, stream, w1, w1t);
    hipLaunchKernelGGL(fused_kernel, dim3(BB), dim3(1024), 0, stream, x, w1t, w2, out);
}

// Round 10
// 803.465 us; speedup vs baseline: 1.1991x; 1.1991x over previous
//
#include <hip/hip_runtime.h>

#define BB  256
#define TT  500
#define ENC 700
#define ENC_PAD 704   // rows 700..703 of w1t are zeros (gather padding target)
#define HID 128

// ---------------------------------------------------------------------------
// Kernel 1: transpose w1 (HID, ENC) -> w1t (ENC_PAD, HID); pad rows = 0
// ---------------------------------------------------------------------------
__global__ __launch_bounds__(128) void transpose_w1_kernel(const float* __restrict__ w1,
                                                           float* __restrict__ w1t) {
    int c = blockIdx.x;      // 0..ENC_PAD-1
    int h = threadIdx.x;     // 0..HID-1
    w1t[c * HID + h] = (c < ENC) ? w1[h * ENC + c] : 0.0f;
}

// ---------------------------------------------------------------------------
// Kernel 2 (spmm4, PROVEN round 1-3): compress + gather sparse binary GEMM,
// bit-exact ascending-column sum order. h layout [b][t][ch]. Reverted
// verbatim after two spmm5 (LDS-staged) failures with unfound root cause.
// ---------------------------------------------------------------------------
__global__ __launch_bounds__(256, 4) void spmm4_kernel(const float* __restrict__ x,
                                                       const float* __restrict__ w1t,
                                                       float* __restrict__ h) {
    __shared__ ushort lists[8][152];                  // wave-private pairs of lists
    const int lane = threadIdx.x & 63;
    const int w = threadIdx.x >> 6;
    const int rbase = blockIdx.x * 8 + w * 2;         // rows rbase, rbase+1 (row = b*TT + t)
    const unsigned long long lt = (1ull << lane) - 1ull;

    // ---- phase 1: load both rows, all 22 dwords issued together ----
    const float* xrowA = x + (size_t)rbase * ENC;
    const float* xrowB = xrowA + ENC;
    float xva[11], xvb[11];
    #pragma unroll
    for (int k = 0; k < 11; ++k) {
        int c = k * 64 + lane;
        xva[k] = (c < ENC) ? xrowA[c] : 0.0f;
    }
    #pragma unroll
    for (int k = 0; k < 11; ++k) {
        int c = k * 64 + lane;
        xvb[k] = (c < ENC) ? xrowB[c] : 0.0f;
    }

    // ---- phase 2: ballot-compact into strictly ascending column lists ----
    int nA = 0, nB = 0;
    #pragma unroll
    for (int k = 0; k < 11; ++k) {
        bool act = (xva[k] != 0.0f);
        unsigned long long m = __ballot(act);
        if (act) {
            int pos = nA + (int)__popcll(m & lt);
            if (pos < 144) lists[2 * w + 0][pos] = (ushort)(k * 64 + lane);
        }
        nA += (int)__popcll(m);
    }
    #pragma unroll
    for (int k = 0; k < 11; ++k) {
        bool act = (xvb[k] != 0.0f);
        unsigned long long m = __ballot(act);
        if (act) {
            int pos = nB + (int)__popcll(m & lt);
            if (pos < 144) lists[2 * w + 1][pos] = (ushort)(k * 64 + lane);
        }
        nB += (int)__popcll(m);
    }
    nA = (nA < 144) ? nA : 144;
    nB = (nB < 144) ? nB : 144;
    int npmax = ((nA > nB ? nA : nB) + 3) & ~3;       // shared trip count, x4
    if (npmax < 4) npmax = 4;
    for (int p = nA + lane; p < npmax + 4; p += 64) lists[2 * w + 0][p] = (ushort)ENC;
    for (int p = nB + lane; p < npmax + 4; p += 64) lists[2 * w + 1][p] = (ushort)ENC;
    // lists are wave-private; in-wave LDS RAW ordered by lgkmcnt.

    // ---- phase 3: half-wave float4 gather, 2-stage pipeline ----
    const int half = lane >> 5;                       // 0 -> row A, 1 -> row B
    const int hl = lane & 31;                         // channel group: 4*hl..4*hl+3
    const ushort* mylist = lists[2 * w + half];
    const float* wb = w1t + 4 * hl;

    float a0 = 0.f, a1 = 0.f, a2 = 0.f, a3 = 0.f;

    int c0 = mylist[0], c1 = mylist[1], c2 = mylist[2], c3 = mylist[3];
    float4 p0 = *(const float4*)(wb + (size_t)c0 * HID);
    float4 p1 = *(const float4*)(wb + (size_t)c1 * HID);
    float4 p2 = *(const float4*)(wb + (size_t)c2 * HID);
    float4 p3 = *(const float4*)(wb + (size_t)c3 * HID);

    for (int j = 0; j < npmax; j += 4) {
        int d0 = mylist[j + 4], d1 = mylist[j + 5];
        int d2 = mylist[j + 6], d3 = mylist[j + 7];
        float4 q0 = *(const float4*)(wb + (size_t)d0 * HID);
        float4 q1 = *(const float4*)(wb + (size_t)d1 * HID);
        float4 q2 = *(const float4*)(wb + (size_t)d2 * HID);
        float4 q3 = *(const float4*)(wb + (size_t)d3 * HID);
        // ordered ascending-column accumulation; 4 independent channel chains
        a0 += p0.x; a1 += p0.y; a2 += p0.z; a3 += p0.w;
        a0 += p1.x; a1 += p1.y; a2 += p1.z; a3 += p1.w;
        a0 += p2.x; a1 += p2.y; a2 += p2.z; a3 += p2.w;
        a0 += p3.x; a1 += p3.y; a2 += p3.z; a3 += p3.w;
        p0 = q0; p1 = q1; p2 = q2; p3 = q3;
    }

    // h layout [b][t][ch]: row r is contiguous at h + r*HID
    const int r = rbase + half;
    float4* dst = (float4*)(h + (size_t)r * HID) + hl;
    *dst = make_float4(a0, a1, a2, a3);
}

// ---------------------------------------------------------------------------
// Kernel 3 (recur v5): 192 threads (3 waves) per b.
//   v1-v3 all measured ~165 us regardless of h-staging scheme -> the cost is
//   the per-chunk SERIAL path: scan(50) -> reduce -> layer2(50) on the same
//   threads. v5 halves that path: waves 0-1 run scan+reduce (identical code);
//   wave 2 runs layer-2 for chunk k-1 CONCURRENTLY with scan of chunk k,
//   with pbuf double-buffered by chunk parity. Layer-2 arithmetic, order and
//   state carry are byte-identical (just executed one chunk later on another
//   wave) -> bit-exact. Barrier sequence uniform across all 3 waves.
//   Races: wave2 reads pbuf[(k-1)&1] in phase 1; reduce writes pbuf[k&1] in
//   phase 3 (other parity, across a barrier); same-parity rewrite happens
//   only after the NEXT body's first barrier. vbuf(k+1) written only after
//   reduce(k)'s trailing barrier.
// ---------------------------------------------------------------------------
__global__ __launch_bounds__(192) void recur_kernel(const float* __restrict__ hgl,
                                                    const float* __restrict__ w2,
                                                    float* __restrict__ out) {
    __shared__ float vbuf[50 * 129];      // stride 129 -> conflict-free rows
    __shared__ float pbuf[2][2][50];      // [chunk parity][wave half][t]

    const int b = blockIdx.x;
    const int tid = threadIdx.x;          // 0..191

    const float D   = 0.95122942450071400910f;                                 // exp(-1/20)
    const float CD  = (float)(0.13591409142295226 * 0.95122942450071400910);   // (e/20)*d
    const float CRD = (float)(-0.27182818284590452 * 0.95122942450071400910);  // (-2e/20)*d

    float ap = 0.f, aq = 0.f, rp = 0.f, rq = 0.f;   // layer-1, channel = tid (<128)
    float Ap = 0.f, Aq = 0.f, Rp = 0.f, Rq = 0.f;   // layer-2, wave 2 only
    const float w2v = (tid < HID) ? w2[tid] : 0.0f;

    const float* hb = hgl + (size_t)b * (TT * HID) + tid;   // used when tid<128

    float hA[50], hB[50];

    // layer-2 for one chunk (wave 2): identical arithmetic to the verified
    // serial version, reading pbuf[chunk&1].
    auto layer2 = [&](int chunk) {
        const int par = chunk & 1;
        const int t2 = tid - 128;         // 0..63
        float my2 = 0.f;
        #pragma unroll
        for (int tl = 0; tl < 50; ++tl) {
            float ot = pbuf[par][0][tl] + pbuf[par][1][tl];
            float y2 = fmaf(D, Aq, CD * Ap);
            Aq = y2;
            Ap = fmaf(D, Ap, ot);
            float q2 = fmaf(D, Rq, CRD * Rp);
            float u2 = y2 + q2;
            float s2 = (u2 >= 1.0f) ? 1.0f : 0.0f;
            Rq = q2;
            Rp = fmaf(D, Rp, s2);
            if (tl == t2) my2 = s2;
        }
        if (t2 < 50) out[(size_t)b * TT + chunk * 50 + t2] = my2;
    };

    // one chunk: [scan(chunk) on waves01 || layer2(chunk-1) on wave2] ->
    // barrier -> reduce(chunk) -> barrier
    auto body = [&](const float (&hv)[50], int chunk) {
        if (tid < 128) {
            #pragma unroll
            for (int tl = 0; tl < 50; ++tl) {
                float h_ = hv[tl];
                float y = fmaf(D, aq, CD * ap);
                aq = y;
                ap = fmaf(D, ap, h_);
                float q = fmaf(D, rq, CRD * rp);
                float u = y + q;
                float s = (u >= 1.0f) ? 1.0f : 0.0f;
                rq = q;
                rp = fmaf(D, rp, s);
                vbuf[tl * 129 + tid] = s * w2v;
            }
        } else if (chunk >= 1) {
            layer2(chunk - 1);
        }
        __syncthreads();   // vbuf(chunk) ready; wave2 done with pbuf[(chunk-1)&1]

        if (tid < 50) {
            const float* row = &vbuf[tid * 129];
            float a0 = 0.f, a1 = 0.f, a2 = 0.f, a3 = 0.f;
            #pragma unroll
            for (int k = 0; k < 64; k += 4) {
                a0 += row[k]; a1 += row[k + 1]; a2 += row[k + 2]; a3 += row[k + 3];
            }
            pbuf[chunk & 1][0][tid] = (a0 + a1) + (a2 + a3);
        } else if (tid >= 64 && tid < 114) {
            const float* row = &vbuf[(tid - 64) * 129 + 64];
            float a0 = 0.f, a1 = 0.f, a2 = 0.f, a3 = 0.f;
            #pragma unroll
            for (int k = 0; k < 64; k += 4) {
                a0 += row[k]; a1 += row[k + 1]; a2 += row[k + 2]; a3 += row[k + 3];
            }
            pbuf[chunk & 1][1][tid - 64] = (a0 + a1) + (a2 + a3);
        }
        __syncthreads();   // pbuf(chunk) ready for wave2 next body
    };

    // prologue: chunk 0 into hA (waves 0-1)
    if (tid < 128) {
        #pragma unroll
        for (int j = 0; j < 50; ++j) hA[j] = hb[j * HID];
    }

    for (int cp = 0; cp < 5; ++cp) {
        if (tid < 128) {
            const float* g = hb + (size_t)(2 * cp + 1) * 50 * HID;
            #pragma unroll
            for (int j = 0; j < 50; ++j) hB[j] = g[j * HID];
        }
        body(hA, 2 * cp);
        if (cp < 4 && tid < 128) {
            const float* g = hb + (size_t)(2 * cp + 2) * 50 * HID;
            #pragma unroll
            for (int j = 0; j < 50; ++j) hA[j] = g[j * HID];
        }
        body(hB, 2 * cp + 1);
    }

    // epilogue: layer-2 for the last chunk (wave 2); pbuf[1] written before
    // the final barrier of body(...,9)
    if (tid >= 128) layer2(9);
}

// ---------------------------------------------------------------------------
extern "C" void kernel_launch(void* const* d_in, const int* in_sizes, int n_in,
                              void* d_out, int out_size, void* d_ws, size_t ws_size,
                              hipStream_t stream) {
    const float* x  = (const float*)d_in[0];   // (B, T, ENC) binary fp32
    const float* w1 = (const float*)d_in[1];   // (HID, ENC)
    const float* w2 = (const float*)d_in[2];   // (1, HID)
    float* out = (float*)d_out;                // (B, T, 1)

    float* h   = (float*)d_ws;                          // (B, T, HID) = 65.5 MB
    float* w1t = h + (size_t)TT * BB * HID;             // (ENC_PAD, HID)

    hipLaunchKernelGGL(transpose_w1_kernel, dim3(ENC_PAD), dim3(HID), 0, stream, w1, w1t);
    hipLaunchKernelGGL(spmm4_kernel, dim3((BB * TT) / 8), dim3(256), 0, stream, x, w1t, h);
    hipLaunchKernelGGL(recur_kernel, dim3(BB), dim3(192), 0, stream, h, w2, out);
}

// Round 11
// 603.433 us; speedup vs baseline: 1.5965x; 1.3315x over previous
//
#include <hip/hip_runtime.h>

#define BB  256
#define TT  500
#define ENC 700
#define ENC_PAD 704   // rows 700..703 of w1t are zeros (gather padding target)
#define HID 128

// ---------------------------------------------------------------------------
// Kernel 1: transpose w1 (HID, ENC) -> w1t (ENC_PAD, HID); pad rows = 0
// ---------------------------------------------------------------------------
__global__ __launch_bounds__(128) void transpose_w1_kernel(const float* __restrict__ w1,
                                                           float* __restrict__ w1t) {
    int c = blockIdx.x;      // 0..ENC_PAD-1
    int h = threadIdx.x;     // 0..HID-1
    w1t[c * HID + h] = (c < ENC) ? w1[h * ENC + c] : 0.0f;
}

// ---------------------------------------------------------------------------
// Kernel 2 (spmm3, PROVEN 221.5 us in round 0): compress + gather sparse
// binary GEMM, bit-exact ascending-column sum order. ONE row per wave
// (128k waves -> full gather TLP; the round-1 2-rows/wave variant halved
// wave count and regressed to 322 us). Only change vs round 0: the store
// goes to h[b][t][ch] (= h[r*HID], same 512 B-contiguous per-wave store
// pattern, different global address) so recur v3 reads a private
// contiguous stream.
// ---------------------------------------------------------------------------
__global__ __launch_bounds__(256) void spmm3_kernel(const float* __restrict__ x,
                                                    const float* __restrict__ w1t,
                                                    float* __restrict__ h) {
    __shared__ ushort lists[4][144];
    const int lane = threadIdx.x & 63;
    const int w = threadIdx.x >> 6;
    const int r = blockIdx.x * 4 + w;                 // row = b*TT + t
    const float* xrow = x + (size_t)r * ENC;
    const unsigned long long lanemask_lt = (1ull << lane) - 1ull;

    // phase 1: load the whole row (independent coalesced dwords, all in flight)
    float xv[11];
    #pragma unroll
    for (int k = 0; k < 11; ++k) {
        int c = k * 64 + lane;
        xv[k] = (c < ENC) ? xrow[c] : 0.0f;
    }

    // phase 2: ballot-compact into ascending-order column list
    int base = 0;
    #pragma unroll
    for (int k = 0; k < 11; ++k) {
        bool act = (xv[k] != 0.0f);
        unsigned long long m = __ballot(act);
        if (act) {
            int pos = base + (int)__popcll(m & lanemask_lt);
            if (pos < 128) lists[w][pos] = (ushort)(k * 64 + lane);
        }
        base += (int)__popcll(m);
    }
    int n = (base < 128) ? base : 128;
    int npad = (n + 15) & ~15;                        // pad to x16 with zero column
    if (lane < npad - n) lists[w][n + lane] = (ushort)ENC;
    __syncthreads();                                  // lists visible to gather

    // phase 3: gather, 16 loads in flight, ordered single-chain accumulation
    float accx = 0.f, accy = 0.f;
    for (int j = 0; j < npad; j += 16) {
        int c0  = lists[w][j +  0], c1  = lists[w][j +  1];
        int c2  = lists[w][j +  2], c3  = lists[w][j +  3];
        int c4  = lists[w][j +  4], c5  = lists[w][j +  5];
        int c6  = lists[w][j +  6], c7  = lists[w][j +  7];
        int c8  = lists[w][j +  8], c9  = lists[w][j +  9];
        int c10 = lists[w][j + 10], c11 = lists[w][j + 11];
        int c12 = lists[w][j + 12], c13 = lists[w][j + 13];
        int c14 = lists[w][j + 14], c15 = lists[w][j + 15];
        float2 t0  = ((const float2*)(w1t + (size_t)c0  * HID))[lane];
        float2 t1  = ((const float2*)(w1t + (size_t)c1  * HID))[lane];
        float2 t2  = ((const float2*)(w1t + (size_t)c2  * HID))[lane];
        float2 t3  = ((const float2*)(w1t + (size_t)c3  * HID))[lane];
        float2 t4  = ((const float2*)(w1t + (size_t)c4  * HID))[lane];
        float2 t5  = ((const float2*)(w1t + (size_t)c5  * HID))[lane];
        float2 t6  = ((const float2*)(w1t + (size_t)c6  * HID))[lane];
        float2 t7  = ((const float2*)(w1t + (size_t)c7  * HID))[lane];
        float2 t8  = ((const float2*)(w1t + (size_t)c8  * HID))[lane];
        float2 t9  = ((const float2*)(w1t + (size_t)c9  * HID))[lane];
        float2 t10 = ((const float2*)(w1t + (size_t)c10 * HID))[lane];
        float2 t11 = ((const float2*)(w1t + (size_t)c11 * HID))[lane];
        float2 t12 = ((const float2*)(w1t + (size_t)c12 * HID))[lane];
        float2 t13 = ((const float2*)(w1t + (size_t)c13 * HID))[lane];
        float2 t14 = ((const float2*)(w1t + (size_t)c14 * HID))[lane];
        float2 t15 = ((const float2*)(w1t + (size_t)c15 * HID))[lane];
        // ordered adds (list order = ascending column order) — do not reassociate
        accx += t0.x;  accy += t0.y;
        accx += t1.x;  accy += t1.y;
        accx += t2.x;  accy += t2.y;
        accx += t3.x;  accy += t3.y;
        accx += t4.x;  accy += t4.y;
        accx += t5.x;  accy += t5.y;
        accx += t6.x;  accy += t6.y;
        accx += t7.x;  accy += t7.y;
        accx += t8.x;  accy += t8.y;
        accx += t9.x;  accy += t9.y;
        accx += t10.x; accy += t10.y;
        accx += t11.x; accy += t11.y;
        accx += t12.x; accy += t12.y;
        accx += t13.x; accy += t13.y;
        accx += t14.x; accy += t14.y;
        accx += t15.x; accy += t15.y;
    }

    // h layout [b][t][ch]: row r contiguous at h + r*HID (512 B/wave store)
    float2* dst = (float2*)(h + (size_t)r * HID);
    dst[lane] = make_float2(accx, accy);
}

// ---------------------------------------------------------------------------
// Kernel 3 (recur v3, PROVEN ~47 us): temporal pipeline per b.
// Block = 128 threads (2 waves), 1 channel/lane; h[b][t][ch] contiguous
// stream prefetched into 50-deep double-buffered register arrays.
// ---------------------------------------------------------------------------
__global__ __launch_bounds__(128) void recur_kernel(const float* __restrict__ hgl,
                                                    const float* __restrict__ w2,
                                                    float* __restrict__ out) {
    __shared__ float vbuf[50 * 129];      // stride 129 -> conflict-free rows
    __shared__ float pbuf[2][50];

    const int b = blockIdx.x;
    const int tid = threadIdx.x;          // 0..127

    const float D   = 0.95122942450071400910f;                                 // exp(-1/20)
    const float CD  = (float)(0.13591409142295226 * 0.95122942450071400910);   // (e/20)*d
    const float CRD = (float)(-0.27182818284590452 * 0.95122942450071400910);  // (-2e/20)*d

    float ap = 0.f, aq = 0.f, rp = 0.f, rq = 0.f;   // layer-1, channel = tid
    float Ap = 0.f, Aq = 0.f, Rp = 0.f, Rq = 0.f;   // layer-2, redundant on all lanes
    const float w2v = w2[tid];

    const float* hb = hgl + (size_t)b * (TT * HID) + tid;

    float hA[50], hB[50];

    auto body = [&](const float (&hv)[50], int chunk) {
        #pragma unroll
        for (int tl = 0; tl < 50; ++tl) {
            float h_ = hv[tl];
            float y = fmaf(D, aq, CD * ap);
            aq = y;
            ap = fmaf(D, ap, h_);
            float q = fmaf(D, rq, CRD * rp);
            float u = y + q;
            float s = (u >= 1.0f) ? 1.0f : 0.0f;
            rq = q;
            rp = fmaf(D, rp, s);
            vbuf[tl * 129 + tid] = s * w2v;
        }
        __syncthreads();

        if (tid < 50) {
            const float* row = &vbuf[tid * 129];
            float a0 = 0.f, a1 = 0.f, a2 = 0.f, a3 = 0.f;
            #pragma unroll
            for (int k = 0; k < 64; k += 4) {
                a0 += row[k]; a1 += row[k + 1]; a2 += row[k + 2]; a3 += row[k + 3];
            }
            pbuf[0][tid] = (a0 + a1) + (a2 + a3);
        } else if (tid >= 64 && tid < 114) {
            const float* row = &vbuf[(tid - 64) * 129 + 64];
            float a0 = 0.f, a1 = 0.f, a2 = 0.f, a3 = 0.f;
            #pragma unroll
            for (int k = 0; k < 64; k += 4) {
                a0 += row[k]; a1 += row[k + 1]; a2 += row[k + 2]; a3 += row[k + 3];
            }
            pbuf[1][tid - 64] = (a0 + a1) + (a2 + a3);
        }
        __syncthreads();

        float my_s2 = 0.f;
        #pragma unroll
        for (int tl = 0; tl < 50; ++tl) {
            float ot = pbuf[0][tl] + pbuf[1][tl];
            float y2 = fmaf(D, Aq, CD * Ap);
            Aq = y2;
            Ap = fmaf(D, Ap, ot);
            float q2 = fmaf(D, Rq, CRD * Rp);
            float u2 = y2 + q2;
            float s2 = (u2 >= 1.0f) ? 1.0f : 0.0f;
            Rq = q2;
            Rp = fmaf(D, Rp, s2);
            if (tl == tid) my_s2 = s2;
        }
        if (tid < 50) out[(size_t)b * TT + chunk * 50 + tid] = my_s2;
    };

    #pragma unroll
    for (int j = 0; j < 50; ++j) hA[j] = hb[j * HID];

    for (int cp = 0; cp < 5; ++cp) {
        {
            const float* g = hb + (size_t)(2 * cp + 1) * 50 * HID;
            #pragma unroll
            for (int j = 0; j < 50; ++j) hB[j] = g[j * HID];
        }
        body(hA, 2 * cp);
        if (cp < 4) {
            const float* g = hb + (size_t)(2 * cp + 2) * 50 * HID;
            #pragma unroll
            for (int j = 0; j < 50; ++j) hA[j] = g[j * HID];
        }
        body(hB, 2 * cp + 1);
    }
}

// ---------------------------------------------------------------------------
extern "C" void kernel_launch(void* const* d_in, const int* in_sizes, int n_in,
                              void* d_out, int out_size, void* d_ws, size_t ws_size,
                              hipStream_t stream) {
    const float* x  = (const float*)d_in[0];   // (B, T, ENC) binary fp32
    const float* w1 = (const float*)d_in[1];   // (HID, ENC)
    const float* w2 = (const float*)d_in[2];   // (1, HID)
    float* out = (float*)d_out;                // (B, T, 1)

    float* h   = (float*)d_ws;                          // (B, T, HID) = 65.5 MB
    float* w1t = h + (size_t)TT * BB * HID;             // (ENC_PAD, HID)

    hipLaunchKernelGGL(transpose_w1_kernel, dim3(ENC_PAD), dim3(HID), 0, stream, w1, w1t);
    hipLaunchKernelGGL(spmm3_kernel, dim3((BB * TT) / 4), dim3(256), 0, stream, x, w1t, h);
    hipLaunchKernelGGL(recur_kernel, dim3(BB), dim3(128), 0, stream, h, w2, out);
}